// Round 11
// baseline (90.364 us; speedup 1.0000x reference)
//
#include <hip/hip_runtime.h>
#include <hip/hip_bf16.h>
#include <math.h>

typedef __attribute__((ext_vector_type(8))) short bf16x8;
typedef __attribute__((ext_vector_type(4))) float f32x4;

#define B_ 4
#define C_ 128

// ---- workspace byte offsets (27,000,832 B total; proven round-8 layout) ----
#define XT1_B   0ull               // bf16 [4][4096][128]           4 MB
#define XTT1_B  4194304ull         // bf16 [4][128][4096]           4 MB
#define OVL_B   8388608ull         // overlap region == o1p (16 MB)
#define XT2_B   (OVL_B + 0ull)
#define XTT2_B  (OVL_B + 1048576ull)
#define XT4_B   (OVL_B + 2097152ull)
#define XTT4_B  (OVL_B + 2359296ull)
#define A2P_B   (OVL_B + 2621440ull)
#define ML2_B   (OVL_B + 11010048ull)
#define A4P_B   (OVL_B + 11272192ull)
#define ML4_B   (OVL_B + 11796480ull)
#define O1P_B   8388608ull         // bf16 [4][4][128][4096]       16 MB
#define ML1_B   25165824ull
#define A2M_B   25690112ull
#define A4M_B   26738688ull

#define LOG2E 1.4426950408889634f

__device__ __forceinline__ float ex2(float x) { return __builtin_amdgcn_exp2f(x); }

__device__ __forceinline__ unsigned short f2bf(float f) {
    unsigned int u = __builtin_bit_cast(unsigned int, f);
    return (unsigned short)((u + 0x7FFFu + ((u >> 16) & 1u)) >> 16);
}
__device__ __forceinline__ float bf2f(unsigned short u) {
    unsigned int x = ((unsigned int)u) << 16;
    return __builtin_bit_cast(float, x);
}
__device__ __forceinline__ unsigned int pkbf(float lo, float hi) {
    union { __hip_bfloat162 h; unsigned int u; } c;
    c.h = __float22bfloat162_rn(make_float2(lo, hi));
    return c.u;
}
__device__ __forceinline__ void gload_lds16(const void* g, void* l) {
    __builtin_amdgcn_global_load_lds(
        (const __attribute__((address_space(1))) unsigned int*)g,
        (__attribute__((address_space(3))) unsigned int*)l, 16, 0, 0);
}

// ---------------- fused pool: x[B][C][64][64] -> {xt,xtT} for scales 1,2,4
__global__ __launch_bounds__(256) void pool_all(const float* __restrict__ x,
                                                unsigned short* __restrict__ xt1,
                                                unsigned short* __restrict__ xtT1,
                                                unsigned short* __restrict__ xt2,
                                                unsigned short* __restrict__ xtT2,
                                                unsigned short* __restrict__ xt4,
                                                unsigned short* __restrict__ xtT4) {
    constexpr int RS = 257;
    __shared__ float lds[32 * RS];
    const int hp4 = blockIdx.x;
    const int c0  = blockIdx.y * 32;
    const int b   = blockIdx.z;
    const int t   = threadIdx.x;

    #pragma unroll
    for (int i = 0; i < 8; ++i) {
        int e4 = (i * 256 + t) * 4;
        int ci = e4 >> 8, rem = e4 & 255;
        float4 v = *reinterpret_cast<const float4*>(
            &x[((size_t)(b * C_ + c0 + ci) * 64 + (hp4 * 4 + (rem >> 6))) * 64 + (rem & 63)]);
        *reinterpret_cast<float4*>(&lds[ci * RS + rem]) = v;
    }
    __syncthreads();

    #pragma unroll
    for (int i = 0; i < 32; ++i) {
        int v = i * 256 + t;
        int ci = v & 31, pos = v >> 5;
        xt1[((size_t)b * 4096 + hp4 * 256 + pos) * C_ + c0 + ci] = f2bf(lds[ci * RS + pos]);
    }
    #pragma unroll
    for (int i = 0; i < 32; ++i) {
        int ci = i, pos = t;
        xtT1[((size_t)(b * C_ + c0 + ci)) * 4096 + hp4 * 256 + pos] = f2bf(lds[ci * RS + pos]);
    }
    #pragma unroll
    for (int i = 0; i < 8; ++i) {
        int v = i * 256 + t;
        int ci = v & 31, pz = v >> 5;
        int r2 = pz >> 5, w2 = pz & 31;
        float s = lds[ci * RS + (2*r2)*64 + 2*w2]     + lds[ci * RS + (2*r2)*64 + 2*w2 + 1]
                + lds[ci * RS + (2*r2+1)*64 + 2*w2]   + lds[ci * RS + (2*r2+1)*64 + 2*w2 + 1];
        xt2[((size_t)b * 1024 + (hp4*2 + r2)*32 + w2) * C_ + c0 + ci] = f2bf(s * 0.25f);
    }
    #pragma unroll
    for (int i = 0; i < 8; ++i) {
        int v = i * 256 + t;
        int pz = v & 63, ci = v >> 6;
        int r2 = pz >> 5, w2 = pz & 31;
        float s = lds[ci * RS + (2*r2)*64 + 2*w2]     + lds[ci * RS + (2*r2)*64 + 2*w2 + 1]
                + lds[ci * RS + (2*r2+1)*64 + 2*w2]   + lds[ci * RS + (2*r2+1)*64 + 2*w2 + 1];
        xtT2[((size_t)(b * C_ + c0 + ci)) * 1024 + (hp4*2 + r2)*32 + w2] = f2bf(s * 0.25f);
    }
    #pragma unroll
    for (int i = 0; i < 2; ++i) {
        int v = i * 256 + t;
        int ci = v & 31, w4 = v >> 5;
        float s = 0.f;
        #pragma unroll
        for (int r = 0; r < 4; ++r)
            #pragma unroll
            for (int j = 0; j < 4; ++j) s += lds[ci * RS + r*64 + w4*4 + j];
        xt4[((size_t)b * 256 + hp4*16 + w4) * C_ + c0 + ci] = f2bf(s * 0.0625f);
    }
    #pragma unroll
    for (int i = 0; i < 2; ++i) {
        int v = i * 256 + t;
        int w4 = v & 15, ci = v >> 4;
        float s = 0.f;
        #pragma unroll
        for (int r = 0; r < 4; ++r)
            #pragma unroll
            for (int j = 0; j < 4; ++j) s += lds[ci * RS + r*64 + w4*4 + j];
        xtT4[((size_t)(b * C_ + c0 + ci)) * 256 + hp4*16 + w4] = f2bf(s * 0.0625f);
    }
}

// ---------------- MFMA flash attention, KVBLK=32, 32 KB LDS -> 4 blocks/CU.
// Same counted-vmcnt dbuf schedule as round 8, ledger rescaled (2-load stages).
// 4 independent blocks per CU drift anti-phase -> cross-pipe overlap + latency cover.
template<int N, int SPLIT>
__device__ __forceinline__ void attn_body(const unsigned short* __restrict__ xt,
                                          const unsigned short* __restrict__ xtT,
                                          unsigned short* __restrict__ op,
                                          float* __restrict__ ml,
                                          const int bid, char* lds) {
    constexpr int LOG2S = (SPLIT == 2) ? 1 : ((SPLIT == 4) ? 2 : 3);
    constexpr int QB = N / 128;
    constexpr int W2 = QB * SPLIT / 2;
    constexpr int NT = N / SPLIT / 32;
    static_assert(NT >= 2 && (NT & 1) == 0, "even NT >= 2 required");
    const int xcd   = bid & 7;
    const int b     = xcd >> 1;                 // batch pinned to XCD pair (L2 locality)
    const int wi    = (xcd & 1) * W2 + (bid >> 3);
    const int split = wi & (SPLIT - 1);
    const int qx    = wi >> LOG2S;
    const int n0    = qx * 128;
    const int m_beg = split * (N / SPLIT);

    const int tid = threadIdx.x;
    const int w = tid >> 6, lane = tid & 63;
    const int g = lane >> 4, rho = lane & 15;

    const char* xb  = (const char*)(xt  + (size_t)b * N * C_);
    const char* xtb = (const char*)(xtT + (size_t)b * C_ * N);

    // Q fragments (B-operand of S^T mfma), pre-scaled by log2e
    bf16x8 qf[2][4];
    #pragma unroll
    for (int tt = 0; tt < 2; ++tt) {
        const char* qr = xb + (size_t)(n0 + w * 32 + tt * 16 + rho) * 256;
        #pragma unroll
        for (int kc = 0; kc < 4; ++kc) {
            bf16x8 raw = *(const bf16x8*)(qr + kc * 64 + g * 16);
            bf16x8 s;
            #pragma unroll
            for (int e = 0; e < 8; ++e)
                s[e] = (short)f2bf(bf2f((unsigned short)raw[e]) * LOG2E);
            qf[tt][kc] = s;
        }
    }

    // per-lane constant offsets.
    // K tile [32 m][128 c] (256 B rows), swizzle (row&15)<<4 (proven).
    // V^T tile [128 c][32 m] (64 B rows), swizzle ((c>>1)&3)<<4 (2-way = free).
    int kOff[2], vOff[2];
    #pragma unroll
    for (int k = 0; k < 2; ++k) {
        int D = (w * 2 + k) * 1024 + lane * 16;
        int row = D >> 8, colb = D & 255;
        kOff[k] = row * 256 + (colb ^ ((row & 15) << 4));
        int c = D >> 6, cb2 = D & 63;
        vOff[k] = c * (2 * N) + (cb2 ^ (((c >> 1) & 3) << 4));
    }
    int qkOff[2][4], pvOff[8];
    #pragma unroll
    for (int mb = 0; mb < 2; ++mb) {
        int rowm = (mb << 2) + ((rho >> 2) << 3) + (rho & 3);
        int swz = (rowm & 15) << 4;
        #pragma unroll
        for (int kc = 0; kc < 4; ++kc)
            qkOff[mb][kc] = rowm * 256 + ((kc * 64 + g * 16) ^ swz);
    }
    #pragma unroll
    for (int cb = 0; cb < 8; ++cb) {
        int c = cb * 16 + rho;
        pvOff[cb] = c * 64 + ((g * 16) ^ (((c >> 1) & 3) << 4));
    }

    char* const KB0 = lds;
    char* const KB1 = lds + 8192;
    char* const VB0 = lds + 16384;
    char* const VB1 = lds + 24576;
    const char* kG = xb  + (size_t)m_beg * 256;
    const char* vG = xtb + (size_t)m_beg * 2;

    auto stageK = [&](char* dst, int tile) {
        const char* s = kG + (size_t)tile * (32 * 256);
        #pragma unroll
        for (int k = 0; k < 2; ++k) gload_lds16(s + kOff[k], dst + (w * 2 + k) * 1024);
    };
    auto stageV = [&](char* dst, int tile) {
        const char* s = vG + (size_t)tile * (32 * 2);
        #pragma unroll
        for (int k = 0; k < 2; ++k) gload_lds16(s + vOff[k], dst + (w * 2 + k) * 1024);
    };

    f32x4 acc[2][8];
    #pragma unroll
    for (int tt = 0; tt < 2; ++tt)
        #pragma unroll
        for (int cb = 0; cb < 8; ++cb) acc[tt][cb] = (f32x4){0.f, 0.f, 0.f, 0.f};
    float m_run[2] = {-INFINITY, -INFINITY};
    float l_lane[2] = {0.f, 0.f};

    auto qkt = [&](const char* kb, f32x4 (&aS)[2][2]) {
        #pragma unroll
        for (int tt = 0; tt < 2; ++tt)
            #pragma unroll
            for (int mb = 0; mb < 2; ++mb) aS[tt][mb] = (f32x4){0.f, 0.f, 0.f, 0.f};
        #pragma unroll
        for (int mb = 0; mb < 2; ++mb)
            #pragma unroll
            for (int kc = 0; kc < 4; ++kc) {
                bf16x8 kf = *(const bf16x8*)(kb + qkOff[mb][kc]);
                aS[0][mb] = __builtin_amdgcn_mfma_f32_16x16x32_bf16(kf, qf[0][kc], aS[0][mb], 0, 0, 0);
                aS[1][mb] = __builtin_amdgcn_mfma_f32_16x16x32_bf16(kf, qf[1][kc], aS[1][mb], 0, 0, 0);
            }
    };

    auto smpv = [&](f32x4 (&aS)[2][2], const char* vb) {
        bf16x8 pb[2];
        #pragma unroll
        for (int tt = 0; tt < 2; ++tt) {
            float tm = aS[tt][0][0];
            #pragma unroll
            for (int mb = 0; mb < 2; ++mb)
                #pragma unroll
                for (int r = 0; r < 4; ++r) tm = fmaxf(tm, aS[tt][mb][r]);
            tm = fmaxf(tm, __shfl_xor(tm, 16));
            tm = fmaxf(tm, __shfl_xor(tm, 32));
            if (!__all(tm <= m_run[tt] + 6.0f)) {
                float nm = fmaxf(m_run[tt], tm);
                float sc = ex2(m_run[tt] - nm);
                l_lane[tt] *= sc;
                m_run[tt] = nm;
                #pragma unroll
                for (int cb = 0; cb < 8; ++cb) {
                    acc[tt][cb][0] *= sc; acc[tt][cb][1] *= sc;
                    acc[tt][cb][2] *= sc; acc[tt][cb][3] *= sc;
                }
            }
            float p[2][4];
            #pragma unroll
            for (int mb = 0; mb < 2; ++mb)
                #pragma unroll
                for (int r = 0; r < 4; ++r) {
                    p[mb][r] = ex2(aS[tt][mb][r] - m_run[tt]);
                    l_lane[tt] += p[mb][r];
                }
            // pack P^T: elem r <- p[0][r] (m=8g+r), elem 4+r <- p[1][r] (m=8g+4+r)
            union { bf16x8 v; unsigned int u[4]; } pk;
            pk.u[0] = pkbf(p[0][0], p[0][1]);
            pk.u[1] = pkbf(p[0][2], p[0][3]);
            pk.u[2] = pkbf(p[1][0], p[1][1]);
            pk.u[3] = pkbf(p[1][2], p[1][3]);
            pb[tt] = pk.v;
        }
        #pragma unroll
        for (int cb = 0; cb < 8; ++cb) {
            bf16x8 vf = *(const bf16x8*)(vb + pvOff[cb]);
            acc[0][cb] = __builtin_amdgcn_mfma_f32_16x16x32_bf16(vf, pb[0], acc[0][cb], 0, 0, 0);
            acc[1][cb] = __builtin_amdgcn_mfma_f32_16x16x32_bf16(vf, pb[1], acc[1][cb], 0, 0, 0);
        }
    };

    f32x4 accA[2][2], accB[2][2];

    // prologue: K0,V0,K1,V1 staged (8 loads); vmcnt ledger: 6/4/2/0
    stageK(KB0, 0); stageV(VB0, 0); stageK(KB1, 1); stageV(VB1, 1);
    asm volatile("s_waitcnt vmcnt(6)" ::: "memory");    // K0 complete
    __builtin_amdgcn_s_barrier();
    qkt(KB0, accA);
    __builtin_amdgcn_s_barrier();                        // all waves done with KB0
    if constexpr (NT > 2) stageK(KB0, 2);

    #pragma unroll 1
    for (int j = 0; j + 3 < NT; j += 2) {
        // body even (tile j): QK^T(j+1) || softmax(j); PV(j)
        asm volatile("s_waitcnt vmcnt(4)" ::: "memory");   // K(j+1), V(j) done
        __builtin_amdgcn_s_barrier();
        qkt(KB1, accB);
        smpv(accA, VB0);
        __builtin_amdgcn_s_barrier();
        stageK(KB1, j + 3);
        stageV(VB0, j + 2);
        // body odd (tile j+1)
        asm volatile("s_waitcnt vmcnt(4)" ::: "memory");   // K(j+2), V(j+1) done
        __builtin_amdgcn_s_barrier();
        qkt(KB0, accA);
        smpv(accB, VB1);
        __builtin_amdgcn_s_barrier();
        if (j + 4 < NT) stageK(KB0, j + 4);
        stageV(VB1, j + 3);
    }
    // final body (tile NT-2): QK^T(NT-1) || softmax(NT-2); PV(NT-2)
    asm volatile("s_waitcnt vmcnt(2)" ::: "memory");
    __builtin_amdgcn_s_barrier();
    qkt(KB1, accB);
    smpv(accA, VB0);
    // last tile NT-1
    asm volatile("s_waitcnt vmcnt(0)" ::: "memory");
    __builtin_amdgcn_s_barrier();
    smpv(accB, VB1);

    // epilogue: reduce l across g-lanes, store unnormalized partials + (m,l)
    #pragma unroll
    for (int tt = 0; tt < 2; ++tt) {
        l_lane[tt] += __shfl_xor(l_lane[tt], 16);
        l_lane[tt] += __shfl_xor(l_lane[tt], 32);
        const int n = n0 + w * 32 + tt * 16 + rho;
        #pragma unroll
        for (int cb = 0; cb < 8; ++cb)
            #pragma unroll
            for (int r = 0; r < 4; ++r)
                op[((size_t)(split * B_ + b) * C_ + cb * 16 + g * 4 + r) * N + n] = f2bf(acc[tt][cb][r]);
        if (g == 0) {
            ml[((size_t)(split * B_ + b) * N + n) * 2 + 0] = m_run[tt];
            ml[((size_t)(split * B_ + b) * N + n) * 2 + 1] = l_lane[tt];
        }
    }
}

__global__ __launch_bounds__(256, 2) void attn_mfma(const unsigned short* __restrict__ xt,
                                                    const unsigned short* __restrict__ xtT,
                                                    unsigned short* __restrict__ op,
                                                    float* __restrict__ ml) {
    __shared__ char lds[32768];
    attn_body<4096, 4>(xt, xtT, op, ml, (int)blockIdx.x, lds);
}

// scale-2 (blocks 0..255) and scale-4 (blocks 256..271) in one launch
__global__ __launch_bounds__(256, 2) void attn_small(const unsigned short* __restrict__ xt2,
                                                     const unsigned short* __restrict__ xtT2,
                                                     unsigned short* __restrict__ a2p,
                                                     float* __restrict__ ml2,
                                                     const unsigned short* __restrict__ xt4,
                                                     const unsigned short* __restrict__ xtT4,
                                                     unsigned short* __restrict__ a4p,
                                                     float* __restrict__ ml4) {
    __shared__ char lds[32768];
    if (blockIdx.x < 256)
        attn_body<1024, 8>(xt2, xtT2, a2p, ml2, (int)blockIdx.x, lds);
    else
        attn_body<256, 2>(xt4, xtT4, a4p, ml4, (int)blockIdx.x - 256, lds);
}

// ---------------- merge partials: scale-2 (8-way) and scale-4 (2-way)
__global__ __launch_bounds__(256) void merge_small(const unsigned short* __restrict__ a2p,
                                                   const float* __restrict__ ml2,
                                                   const unsigned short* __restrict__ a4p,
                                                   const float* __restrict__ ml4,
                                                   unsigned short* __restrict__ a2m,
                                                   unsigned short* __restrict__ a4m) {
    int idx = blockIdx.x * 256 + threadIdx.x;
    if (idx < 4 * 128 * 1024) {
        int n = idx & 1023, c = (idx >> 10) & 127, b = idx >> 17;
        float M = -INFINITY;
        #pragma unroll
        for (int s = 0; s < 8; ++s) M = fmaxf(M, ml2[((s * 4 + b) * 1024 + n) * 2]);
        float L = 0.f, O = 0.f;
        #pragma unroll
        for (int s = 0; s < 8; ++s) {
            float wgt = ex2(ml2[((s * 4 + b) * 1024 + n) * 2] - M);
            L += ml2[((s * 4 + b) * 1024 + n) * 2 + 1] * wgt;
            O += bf2f(a2p[((size_t)((s * 4 + b) * 128 + c)) * 1024 + n]) * wgt;
        }
        a2m[((size_t)(b * 128 + c)) * 1024 + n] = f2bf(O / L);
    } else {
        int i2 = idx - 4 * 128 * 1024;
        if (i2 < 4 * 128 * 256) {
            int n = i2 & 255, c = (i2 >> 8) & 127, b = i2 >> 15;
            float M = fmaxf(ml4[((0 * 4 + b) * 256 + n) * 2], ml4[((1 * 4 + b) * 256 + n) * 2]);
            float L = 0.f, O = 0.f;
            #pragma unroll
            for (int s = 0; s < 2; ++s) {
                float wgt = ex2(ml4[((s * 4 + b) * 256 + n) * 2] - M);
                L += ml4[((s * 4 + b) * 256 + n) * 2 + 1] * wgt;
                O += bf2f(a4p[((size_t)((s * 4 + b) * 128 + c)) * 256 + n]) * wgt;
            }
            a4m[((size_t)(b * 128 + c)) * 256 + n] = f2bf(O / L);
        }
    }
}

// ---------------- bilinear upsample (half-pixel centers, clamp) from bf16 grid
template<int HS>
__device__ __forceinline__ float bilin(const unsigned short* __restrict__ a, int h, int w) {
    constexpr float sc = (float)HS / 64.0f;
    float sh = (h + 0.5f) * sc - 0.5f;
    float sw = (w + 0.5f) * sc - 0.5f;
    int h0 = (int)floorf(sh); float fh = sh - (float)h0;
    int w0 = (int)floorf(sw); float fw = sw - (float)w0;
    int h0c = max(h0, 0), h1c = min(h0 + 1, HS - 1);
    int w0c = max(w0, 0), w1c = min(w0 + 1, HS - 1);
    float v00 = bf2f(a[h0c * HS + w0c]), v01 = bf2f(a[h0c * HS + w1c]);
    float v10 = bf2f(a[h1c * HS + w0c]), v11 = bf2f(a[h1c * HS + w1c]);
    return (1.f - fh) * ((1.f - fw) * v00 + fw * v01)
         +        fh  * ((1.f - fw) * v10 + fw * v11);
}

__global__ __launch_bounds__(256) void combine_kernel(float* __restrict__ out,
                                                      const unsigned short* __restrict__ o1p,
                                                      const float* __restrict__ ml1,
                                                      const unsigned short* __restrict__ a2m,
                                                      const unsigned short* __restrict__ a4m) {
    int e = blockIdx.x * 256 + threadIdx.x;
    if (e >= B_ * C_ * 64 * 64) return;
    int w  = e & 63;
    int h  = (e >> 6) & 63;
    int bc = e >> 12;
    int b  = bc >> 7;
    int n  = (h << 6) | w;
    float M = -INFINITY;
    #pragma unroll
    for (int s = 0; s < 4; ++s) M = fmaxf(M, ml1[((size_t)(s * 4 + b) * 4096 + n) * 2]);
    float num = 0.f, den = 0.f;
    #pragma unroll
    for (int s = 0; s < 4; ++s) {
        float wgt = ex2(ml1[((size_t)(s * 4 + b) * 4096 + n) * 2] - M);
        den += ml1[((size_t)(s * 4 + b) * 4096 + n) * 2 + 1] * wgt;
        num += bf2f(o1p[((size_t)(s * 512 + bc)) * 4096 + n]) * wgt;
    }
    float v = num / den;
    v += bilin<32>(a2m + (size_t)bc * 1024, h, w);
    v += bilin<16>(a4m + (size_t)bc * 256,  h, w);
    out[e] = v;
}

extern "C" void kernel_launch(void* const* d_in, const int* in_sizes, int n_in,
                              void* d_out, int out_size, void* d_ws, size_t ws_size,
                              hipStream_t stream) {
    const float* x = (const float*)d_in[0];
    float* out = (float*)d_out;
    char* ws = (char*)d_ws;
    unsigned short* xt1  = (unsigned short*)(ws + XT1_B);
    unsigned short* xtT1 = (unsigned short*)(ws + XTT1_B);
    unsigned short* xt2  = (unsigned short*)(ws + XT2_B);
    unsigned short* xtT2 = (unsigned short*)(ws + XTT2_B);
    unsigned short* xt4  = (unsigned short*)(ws + XT4_B);
    unsigned short* xtT4 = (unsigned short*)(ws + XTT4_B);
    unsigned short* a2p  = (unsigned short*)(ws + A2P_B);
    float*          ml2  = (float*)(ws + ML2_B);
    unsigned short* a4p  = (unsigned short*)(ws + A4P_B);
    float*          ml4  = (float*)(ws + ML4_B);
    unsigned short* o1p  = (unsigned short*)(ws + O1P_B);
    float*          ml1  = (float*)(ws + ML1_B);
    unsigned short* a2m  = (unsigned short*)(ws + A2M_B);
    unsigned short* a4m  = (unsigned short*)(ws + A4M_B);

    // Phase A: fused pool + small scales (one launch) + their merge
    pool_all<<<dim3(16, 4, B_), 256, 0, stream>>>(x, xt1, xtT1, xt2, xtT2, xt4, xtT4);
    attn_small<<<272, 256, 0, stream>>>(xt2, xtT2, a2p, ml2, xt4, xtT4, a4p, ml4);
    merge_small<<<2560, 256, 0, stream>>>(a2p, ml2, a4p, ml4, a2m, a4m);

    // Phase B: scale-1 (o1p overwrites the overlap region) + final combine
    attn_mfma<<<512, 256, 0, stream>>>(xt1, xtT1, o1p, ml1);
    combine_kernel<<<(B_ * C_ * 64 * 64 + 255) / 256, 256, 0, stream>>>(out, o1p, ml1, a2m, a4m);
}